// Round 10
// baseline (448.154 us; speedup 1.0000x reference)
//
#include <hip/hip_runtime.h>
#include <math.h>

constexpr int IN_CH = 256;
constexpr int HID   = 128;
constexpr int LAT   = 64;

constexpr int BKT_NODES = 128;   // nodes per bucket
constexpr int NSHARD    = 8;     // one shard per XCD (blockIdx & 7 heuristic)
constexpr int CELL_CAP  = 448;   // per (bucket,shard) cell capacity: Poisson(256) +12 sigma
constexpr int BKT_SLOT  = NSHARD * CELL_CAP;   // 3584: bucket region in bedge/csr (aliased)
constexpr int BCAP      = 3072;  // per-bucket LDS edge capacity (mean 2048, +22 sigma)

typedef unsigned short u16;
typedef unsigned int   u32;
typedef __bf16  bf16x8 __attribute__((ext_vector_type(8)));
typedef float   f32x4  __attribute__((ext_vector_type(4)));

__device__ inline u16 f2bf(float f) {
    unsigned u = __float_as_uint(f);
    unsigned r = u + 0x7FFF + ((u >> 16) & 1);
    return (u16)(r >> 16);
}
__device__ inline float bf2f(u16 h) {
    return __uint_as_float((unsigned)h << 16);
}

// ---------------- CSR build pieces ----------------

__global__ void k_zero(int* p, int n) {
    int i = blockIdx.x * blockDim.x + threadIdx.x;
    if (i < n) p[i] = 0;
}

// bin body: one block bins 1024 edges into (bucket, shard) cells
__device__ inline void bin_body(int bin_id, int shard,
                                const int* __restrict__ esrc, const int* __restrict__ edst,
                                int* __restrict__ fill, u32* __restrict__ bedge,
                                int E, int NB) {
#pragma unroll
    for (int j = 0; j < 2; ++j) {
        int e = bin_id * 1024 + j * 512 + threadIdx.x;
        if (e < E) {
            int d = edst[e];
            int b = d >> 7;
            int slot = atomicAdd(&fill[(shard * NB + b) << 4], 1);
            if (slot < CELL_CAP)
                bedge[(size_t)(b * NSHARD + shard) * CELL_CAP + slot] =
                    (u32)esrc[e] | ((u32)(d & 127) << 17);
        }
    }
}

// per-bucket counting sort, fully in LDS; emits csr_src slotted IN PLACE over bedge,
// plus row_ptr/row_end/dinv.
__launch_bounds__(256)
__global__ void k_bsort(const int* __restrict__ fill, u32* __restrict__ bedge,
                        int* __restrict__ row_ptr, int* __restrict__ row_end,
                        float* __restrict__ dinv, int N, int NB) {
    __shared__ u32 buf[BCAP];
    __shared__ int lsrc[BCAP];
    __shared__ int cnt[BKT_NODES], sc[BKT_NODES], excl[BKT_NODES], fillb[BKT_NODES];

    const int b = blockIdx.x, t = threadIdx.x;
    const int node0 = b * BKT_NODES;
    const int nb = min(BKT_NODES, N - node0);
    const int base = b * BKT_SLOT;

    int ccnt[NSHARD], cbase[NSHARD];
    int m = 0;
#pragma unroll
    for (int s = 0; s < NSHARD; ++s) {
        int c = fill[(s * NB + b) << 4];
        c = min(c, CELL_CAP);
        ccnt[s] = c;
        cbase[s] = m;
        m += c;
    }
    if (m > BCAP) m = BCAP;   // +22 sigma impossible; avoid corruption

    for (int j = t; j < BKT_NODES; j += 256) { cnt[j] = 0; fillb[j] = 0; }
    __syncthreads();

    for (int i = t; i < m; i += 256) {
        int s = 0;
#pragma unroll
        for (int j = 1; j < NSHARD; ++j) if (i >= cbase[j]) s = j;
        u32 p = bedge[(size_t)(b * NSHARD + s) * CELL_CAP + (i - cbase[s])];
        buf[i] = p;
        atomicAdd(&cnt[p >> 17], 1);
    }
    __syncthreads();   // all bedge reads for this bucket complete here

    if (t < BKT_NODES) sc[t] = cnt[t];
    __syncthreads();
#pragma unroll
    for (int off = 1; off < BKT_NODES; off <<= 1) {
        int u = 0;
        if (t < BKT_NODES && t >= off) u = sc[t - off];
        __syncthreads();
        if (t < BKT_NODES) sc[t] += u;
        __syncthreads();
    }
    if (t < BKT_NODES) {
        int ex = sc[t] - cnt[t];
        excl[t] = ex;
        if (t < nb) {
            row_ptr[node0 + t] = base + ex;
            row_end[node0 + t] = base + sc[t];
            dinv[node0 + t]    = rsqrtf((float)(cnt[t] + 1));   // +1 self-loop
        }
    }
    __syncthreads();

    for (int i = t; i < m; i += 256) {
        u32 p = buf[i];
        int d7 = p >> 17;
        int slot = atomicAdd(&fillb[d7], 1);
        lsrc[excl[d7] + slot] = (int)(p & 0x1FFFF);
    }
    __syncthreads();

    int* csr = (int*)bedge;
    for (int i = t; i < m; i += 256) csr[base + i] = lsrc[i];
}

// ---------------- W split: f32 -> (hi, lo) bf16 ----------------

__global__ void k_split_w(const float* __restrict__ W, u16* __restrict__ Wh,
                          u16* __restrict__ Wl, int n) {
    int i = blockIdx.x * blockDim.x + threadIdx.x;
    if (i < n) {
        float v = W[i];
        u16 h = f2bf(v);
        Wh[i] = h;
        Wl[i] = f2bf(v - bf2f(h));
    }
}

// ---------------- MFMA GEMM body: h = bf16( (A @ W^T) [* dinv] ), slab-major output ----
// split-bf16 x3: acc += Ah*Wh + Ah*Wl + Al*Wh (f32 accumulate).
// h stored as h[slab][node][SLABW] with SLABW = 16 (NOUT=128) / 8 (NOUT=64).

template<int K, int NOUT, bool USE_DINV>
__device__ inline void gemm_body(int bid,
                                 const float* __restrict__ A,
                                 const u16* __restrict__ Wh,
                                 const u16* __restrict__ Wl,
                                 const float* __restrict__ dinv,
                                 u16* __restrict__ h_out,
                                 int M) {
    constexpr int BM = 64, BK = 32, LDT = 40, THREADS = 512;
    constexpr int WAVES_N  = (NOUT == 128) ? 4 : 2;
    constexpr int WAVES_M  = 8 / WAVES_N;
    constexpr int WM       = BM / WAVES_M;
    constexpr int WN       = 32;
    constexpr int MF       = WM / 16;
    constexpr int NF       = WN / 16;
    constexpr int SLABW    = (NOUT == 128) ? 16 : 8;

    __shared__ u16 Ah[BM][LDT],   Al[BM][LDT];
    __shared__ u16 Bh[NOUT][LDT], Bl[NOUT][LDT];

    const int t    = threadIdx.x;
    const int lane = t & 63;
    const int wid  = t >> 6;
    const int wm   = (wid / WAVES_N) * WM;
    const int wn   = (wid % WAVES_N) * WN;
    const int lr   = lane & 15;
    const int lk   = (lane >> 4) * 8;
    const int row0 = bid * BM;

    f32x4 acc[MF][NF];
#pragma unroll
    for (int i = 0; i < MF; ++i)
#pragma unroll
        for (int j = 0; j < NF; ++j) acc[i][j] = (f32x4)(0.f);

    for (int k0 = 0; k0 < K; k0 += BK) {
        {
            int r  = t >> 3;
            int c4 = (t & 7) * 4;
            int gr = row0 + r;
            float4 v = make_float4(0.f, 0.f, 0.f, 0.f);
            if (gr < M) v = *(const float4*)&A[(size_t)gr * K + k0 + c4];
            ushort4 hi, lo;
            hi.x = f2bf(v.x); lo.x = f2bf(v.x - bf2f(hi.x));
            hi.y = f2bf(v.y); lo.y = f2bf(v.y - bf2f(hi.y));
            hi.z = f2bf(v.z); lo.z = f2bf(v.z - bf2f(hi.z));
            hi.w = f2bf(v.w); lo.w = f2bf(v.w - bf2f(hi.w));
            *(ushort4*)&Ah[r][c4] = hi;
            *(ushort4*)&Al[r][c4] = lo;
        }
#pragma unroll
        for (int it = 0; it < (NOUT * BK / 4) / THREADS; ++it) {
            int q  = it * THREADS + t;
            int r  = q >> 3;
            int c4 = (q & 7) * 4;
            *(ushort4*)&Bh[r][c4] = *(const ushort4*)&Wh[(size_t)r * K + k0 + c4];
            *(ushort4*)&Bl[r][c4] = *(const ushort4*)&Wl[(size_t)r * K + k0 + c4];
        }
        __syncthreads();

        bf16x8 ah[MF], al[MF], bh[NF], bl[NF];
#pragma unroll
        for (int mf = 0; mf < MF; ++mf) {
            ah[mf] = *(const bf16x8*)&Ah[wm + mf * 16 + lr][lk];
            al[mf] = *(const bf16x8*)&Al[wm + mf * 16 + lr][lk];
        }
#pragma unroll
        for (int nf = 0; nf < NF; ++nf) {
            bh[nf] = *(const bf16x8*)&Bh[wn + nf * 16 + lr][lk];
            bl[nf] = *(const bf16x8*)&Bl[wn + nf * 16 + lr][lk];
        }
#pragma unroll
        for (int mf = 0; mf < MF; ++mf)
#pragma unroll
            for (int nf = 0; nf < NF; ++nf) {
                acc[mf][nf] = __builtin_amdgcn_mfma_f32_16x16x32_bf16(ah[mf], bh[nf], acc[mf][nf], 0, 0, 0);
                acc[mf][nf] = __builtin_amdgcn_mfma_f32_16x16x32_bf16(ah[mf], bl[nf], acc[mf][nf], 0, 0, 0);
                acc[mf][nf] = __builtin_amdgcn_mfma_f32_16x16x32_bf16(al[mf], bh[nf], acc[mf][nf], 0, 0, 0);
            }
        __syncthreads();
    }

#pragma unroll
    for (int mf = 0; mf < MF; ++mf) {
#pragma unroll
        for (int r = 0; r < 4; ++r) {
            int grow = row0 + wm + mf * 16 + (lane >> 4) * 4 + r;
            if (grow < M) {
                float dv = USE_DINV ? dinv[grow] : 1.0f;
#pragma unroll
                for (int nf = 0; nf < NF; ++nf) {
                    int col = wn + nf * 16 + lr;
                    h_out[((size_t)(col / SLABW) * M + grow) * SLABW + (col % SLABW)]
                        = f2bf(acc[mf][nf][r] * dv);
                }
            }
        }
    }
}

// fused: groups of 16 blocks = 8 gemm1 + 8 bin, both types on every XCD.
// gemm1 stores RAW h1 (no dinv: dinv not computed yet -> agg1 applies dinv[src]).
__launch_bounds__(512, 4)
__global__ void k_bin_gemm1(const int* __restrict__ esrc, const int* __restrict__ edst,
                            int* __restrict__ fill, u32* __restrict__ bedge,
                            const float* __restrict__ A,
                            const u16* __restrict__ Wh, const u16* __restrict__ Wl,
                            u16* __restrict__ h_out,
                            int E, int NB, int M) {
    int g   = blockIdx.x;
    int vid = ((g >> 4) << 3) | (g & 7);
    if ((g & 15) >= 8) {
        bin_body(vid, g & 7, esrc, edst, fill, bedge, E, NB);
    } else {
        gemm_body<IN_CH, HID, false>(vid, A, Wh, Wl, nullptr, h_out, M);
    }
}

__launch_bounds__(512, 4)
__global__ void k_gemm2(const float* __restrict__ A,
                        const u16* __restrict__ Wh, const u16* __restrict__ Wl,
                        const float* __restrict__ dinv, u16* __restrict__ h_out, int M) {
    gemm_body<HID, LAT, true>(blockIdx.x, A, Wh, Wl, dinv, h_out, M);
}

// ---------------- slab aggregates ----------------
// h tables are slab-major: each XCD (blockIdx&7) gathers only from its own slab,
// which fits its private L2 (3.2 MB / 1.6 MB). csr streamed nontemporal.

__device__ inline void acc8s(float* a, uint4 v, float d) {
    a[0] = fmaf(__uint_as_float(v.x << 16),          d, a[0]);
    a[1] = fmaf(__uint_as_float(v.x & 0xFFFF0000u),  d, a[1]);
    a[2] = fmaf(__uint_as_float(v.y << 16),          d, a[2]);
    a[3] = fmaf(__uint_as_float(v.y & 0xFFFF0000u),  d, a[3]);
    a[4] = fmaf(__uint_as_float(v.z << 16),          d, a[4]);
    a[5] = fmaf(__uint_as_float(v.z & 0xFFFF0000u),  d, a[5]);
    a[6] = fmaf(__uint_as_float(v.w << 16),          d, a[6]);
    a[7] = fmaf(__uint_as_float(v.w & 0xFFFF0000u),  d, a[7]);
}

// agg1: C=128, slab=16ch, 2 threads/node (8ch each), 128 nodes/block.
// h1 is RAW: per-edge multiply by dinv[src]; out1 = relu(dinv_i*sum + b1), node-major f32.
__global__ void k_agg_slab16(const int* __restrict__ row_ptr, const int* __restrict__ row_end,
                             const int* __restrict__ csr,
                             const u16* __restrict__ hs, const float* __restrict__ dinv,
                             const float* __restrict__ bias, float* __restrict__ out, int n) {
    int slab = blockIdx.x & 7;
    int node = (blockIdx.x >> 3) * 128 + (threadIdx.x >> 1);
    if (node >= n) return;
    int half = threadIdx.x & 1;
    const u16* base = hs + (size_t)slab * n * 16 + half * 8;

    int k   = row_ptr[node];
    int end = row_end[node];

    float a[8] = {0.f, 0.f, 0.f, 0.f, 0.f, 0.f, 0.f, 0.f};
    float dvn = dinv[node];
    acc8s(a, *(const uint4*)&base[(size_t)node * 16], dvn);   // self-loop: h_raw[i]*dinv[i]

    for (; k + 4 <= end; k += 4) {
        int s0 = __builtin_nontemporal_load(csr + k);
        int s1 = __builtin_nontemporal_load(csr + k + 1);
        int s2 = __builtin_nontemporal_load(csr + k + 2);
        int s3 = __builtin_nontemporal_load(csr + k + 3);
        float d0 = dinv[s0], d1 = dinv[s1], d2 = dinv[s2], d3 = dinv[s3];
        uint4 v0 = *(const uint4*)&base[(size_t)s0 * 16];
        uint4 v1 = *(const uint4*)&base[(size_t)s1 * 16];
        uint4 v2 = *(const uint4*)&base[(size_t)s2 * 16];
        uint4 v3 = *(const uint4*)&base[(size_t)s3 * 16];
        acc8s(a, v0, d0); acc8s(a, v1, d1); acc8s(a, v2, d2); acc8s(a, v3, d3);
    }
    for (; k < end; ++k) {
        int s0 = __builtin_nontemporal_load(csr + k);
        acc8s(a, *(const uint4*)&base[(size_t)s0 * 16], dinv[s0]);
    }

    int c0 = slab * 16 + half * 8;
    float4 b0 = *(const float4*)&bias[c0];
    float4 b1 = *(const float4*)&bias[c0 + 4];
    f32x4 o0, o1;
    o0[0] = fmaxf(fmaf(a[0], dvn, b0.x), 0.f);
    o0[1] = fmaxf(fmaf(a[1], dvn, b0.y), 0.f);
    o0[2] = fmaxf(fmaf(a[2], dvn, b0.z), 0.f);
    o0[3] = fmaxf(fmaf(a[3], dvn, b0.w), 0.f);
    o1[0] = fmaxf(fmaf(a[4], dvn, b1.x), 0.f);
    o1[1] = fmaxf(fmaf(a[5], dvn, b1.y), 0.f);
    o1[2] = fmaxf(fmaf(a[6], dvn, b1.z), 0.f);
    o1[3] = fmaxf(fmaf(a[7], dvn, b1.w), 0.f);
    __builtin_nontemporal_store(o0, (f32x4*)&out[(size_t)node * HID + c0]);
    __builtin_nontemporal_store(o1, (f32x4*)&out[(size_t)node * HID + c0 + 4]);
}

// agg2: C=64, slab=8ch, 1 thread/node, 256 nodes/block. h2 already has dinv folded.
__global__ void k_agg_slab8(const int* __restrict__ row_ptr, const int* __restrict__ row_end,
                            const int* __restrict__ csr,
                            const u16* __restrict__ hs, const float* __restrict__ dinv,
                            const float* __restrict__ bias, float* __restrict__ out, int n) {
    int slab = blockIdx.x & 7;
    int node = (blockIdx.x >> 3) * 256 + threadIdx.x;
    if (node >= n) return;
    const u16* base = hs + (size_t)slab * n * 8;

    int k   = row_ptr[node];
    int end = row_end[node];

    float a[8] = {0.f, 0.f, 0.f, 0.f, 0.f, 0.f, 0.f, 0.f};
    acc8s(a, *(const uint4*)&base[(size_t)node * 8], 1.0f);   // self-loop term

    for (; k + 4 <= end; k += 4) {
        int s0 = __builtin_nontemporal_load(csr + k);
        int s1 = __builtin_nontemporal_load(csr + k + 1);
        int s2 = __builtin_nontemporal_load(csr + k + 2);
        int s3 = __builtin_nontemporal_load(csr + k + 3);
        uint4 v0 = *(const uint4*)&base[(size_t)s0 * 8];
        uint4 v1 = *(const uint4*)&base[(size_t)s1 * 8];
        uint4 v2 = *(const uint4*)&base[(size_t)s2 * 8];
        uint4 v3 = *(const uint4*)&base[(size_t)s3 * 8];
        acc8s(a, v0, 1.0f); acc8s(a, v1, 1.0f); acc8s(a, v2, 1.0f); acc8s(a, v3, 1.0f);
    }
    for (; k < end; ++k) {
        int s0 = __builtin_nontemporal_load(csr + k);
        acc8s(a, *(const uint4*)&base[(size_t)s0 * 8], 1.0f);
    }

    float dvn = dinv[node];
    int c0 = slab * 8;
    float4 b0 = *(const float4*)&bias[c0];
    float4 b1 = *(const float4*)&bias[c0 + 4];
    f32x4 o0, o1;
    o0[0] = fmaf(a[0], dvn, b0.x);
    o0[1] = fmaf(a[1], dvn, b0.y);
    o0[2] = fmaf(a[2], dvn, b0.z);
    o0[3] = fmaf(a[3], dvn, b0.w);
    o1[0] = fmaf(a[4], dvn, b1.x);
    o1[1] = fmaf(a[5], dvn, b1.y);
    o1[2] = fmaf(a[6], dvn, b1.z);
    o1[3] = fmaf(a[7], dvn, b1.w);
    __builtin_nontemporal_store(o0, (f32x4*)&out[(size_t)node * LAT + c0]);
    __builtin_nontemporal_store(o1, (f32x4*)&out[(size_t)node * LAT + c0 + 4]);
}

// ---------------- launch ----------------

extern "C" void kernel_launch(void* const* d_in, const int* in_sizes, int n_in,
                              void* d_out, int out_size, void* d_ws, size_t ws_size,
                              hipStream_t stream) {
    const float* x   = (const float*)d_in[0];
    const int*   ei  = (const int*)d_in[1];     // harness delivers integers as int32
    const float* W1  = (const float*)d_in[2];
    const float* b1  = (const float*)d_in[3];
    const float* W2  = (const float*)d_in[4];
    const float* b2  = (const float*)d_in[5];
    float*       out = (float*)d_out;

    const int N = in_sizes[0] / IN_CH;
    const int E = in_sizes[1] / 2;
    const int* esrc = ei;
    const int* edst = ei + E;

    const int NB = (N + BKT_NODES - 1) / BKT_NODES;   // buckets

    char* ws = (char*)d_ws;
    int*   fill    = (int*)ws;    ws += (size_t)NB * NSHARD * 16 * 4;  // line-padded counters
    u32*   bedge   = (u32*)ws;    ws += (size_t)NB * BKT_SLOT * 4;     // slotted edges; csr in place
    int*   row_ptr = (int*)ws;    ws += (size_t)N * 4;
    int*   row_end = (int*)ws;    ws += (size_t)N * 4;
    float* dinv    = (float*)ws;  ws += (size_t)N * 4;
    u16*   W1h     = (u16*)ws;    ws += (size_t)HID * IN_CH * 2;
    u16*   W1l     = (u16*)ws;    ws += (size_t)HID * IN_CH * 2;
    u16*   W2h     = (u16*)ws;    ws += (size_t)LAT * HID * 2;
    u16*   W2l     = (u16*)ws;    ws += (size_t)LAT * HID * 2;
    u16*   h1s     = (u16*)ws;    ws += (size_t)N * HID * 2;   // slab-major bf16 (RAW, layer 1)
    u16*   h2s     = (u16*)ws;    ws += (size_t)N * LAT * 2;   // slab-major bf16 (layer 2, *dinv)
    float* out1    = (float*)ws;  ws += (size_t)N * HID * 4;   // agg1 output (f32, GEMM2's A)
    const int* csr_src = (const int*)bedge;                    // aliased (bsort flushes in place)

    dim3 blk(256);

    const int GB = (N + 63) / 64;                 // gemm1 blocks
    const int BB = (E + 1023) / 1024;             // bin blocks
    const int NG = (max(GB, BB) + 7) / 8;         // 16-block groups (8 gemm + 8 bin)

    // ---- prep ----
    k_zero   <<<(NB * NSHARD * 16 + 255) / 256, blk, 0, stream>>>(fill, NB * NSHARD * 16);
    k_split_w<<<(HID * IN_CH + 255) / 256, blk, 0, stream>>>(W1, W1h, W1l, HID * IN_CH);
    k_split_w<<<(LAT * HID + 255) / 256, blk, 0, stream>>>(W2, W2h, W2l, LAT * HID);

    // ---- fused: edge binning (latency-bound) || gemm1 (MFMA-bound) ----
    k_bin_gemm1<<<NG * 16, dim3(512), 0, stream>>>(esrc, edst, fill, bedge,
                                                   x, W1h, W1l, h1s, E, NB, N);

    // ---- CSR finalize (counting sort in LDS) ----
    k_bsort<<<NB, blk, 0, stream>>>(fill, bedge, row_ptr, row_end, dinv, N, NB);

    // ---- layer 1 aggregate (XCD-local slabs; applies dinv[src] and dinv[node]) ----
    k_agg_slab16<<<((N + 127) / 128) * 8, blk, 0, stream>>>(
        row_ptr, row_end, csr_src, h1s, dinv, b1, out1, N);

    // ---- layer 2 ----
    k_gemm2<<<GB, dim3(512), 0, stream>>>(out1, W2h, W2l, dinv, h2s, N);
    k_agg_slab8<<<((N + 255) / 256) * 8, blk, 0, stream>>>(
        row_ptr, row_end, csr_src, h2s, dinv, b2, out, N);
}

// Round 11
// 212.640 us; speedup vs baseline: 2.1076x; 2.1076x over previous
//
#include <hip/hip_runtime.h>
#include <math.h>

constexpr int IN_CH = 256;
constexpr int HID   = 128;
constexpr int LAT   = 64;

constexpr int BKT_NODES = 128;   // nodes per bucket
constexpr int NSHARD    = 8;     // one shard per XCD (blockIdx & 7 heuristic)
constexpr int CELL_CAP  = 448;   // per (bucket,shard) cell capacity: Poisson(256) +12 sigma
constexpr int BKT_SLOT  = NSHARD * CELL_CAP;   // 3584: bucket region in bedge/csr (aliased)
constexpr int BCAP      = 3072;  // per-bucket LDS edge capacity (mean 2048, +22 sigma)

typedef unsigned short u16;
typedef unsigned int   u32;
typedef __bf16  bf16x8 __attribute__((ext_vector_type(8)));
typedef float   f32x4  __attribute__((ext_vector_type(4)));

__device__ inline u16 f2bf(float f) {
    unsigned u = __float_as_uint(f);
    unsigned r = u + 0x7FFF + ((u >> 16) & 1);
    return (u16)(r >> 16);
}
__device__ inline float bf2f(u16 h) {
    return __uint_as_float((unsigned)h << 16);
}

// ---------------- CSR build pieces ----------------

__global__ void k_zero(int* p, int n) {
    int i = blockIdx.x * blockDim.x + threadIdx.x;
    if (i < n) p[i] = 0;
}

// bin body: one block bins 1024 edges into (bucket, shard) cells
__device__ inline void bin_body(int bin_id, int shard,
                                const int* __restrict__ esrc, const int* __restrict__ edst,
                                int* __restrict__ fill, u32* __restrict__ bedge,
                                int E, int NB) {
#pragma unroll
    for (int j = 0; j < 2; ++j) {
        int e = bin_id * 1024 + j * 512 + threadIdx.x;
        if (e < E) {
            int d = edst[e];
            int b = d >> 7;
            int slot = atomicAdd(&fill[(shard * NB + b) << 4], 1);
            if (slot < CELL_CAP)
                bedge[(size_t)(b * NSHARD + shard) * CELL_CAP + slot] =
                    (u32)esrc[e] | ((u32)(d & 127) << 17);
        }
    }
}

// per-bucket counting sort, fully in LDS; emits csr_src slotted IN PLACE over bedge,
// plus row_ptr/row_end/dinv.
__launch_bounds__(256)
__global__ void k_bsort(const int* __restrict__ fill, u32* __restrict__ bedge,
                        int* __restrict__ row_ptr, int* __restrict__ row_end,
                        float* __restrict__ dinv, int N, int NB) {
    __shared__ u32 buf[BCAP];
    __shared__ int lsrc[BCAP];
    __shared__ int cnt[BKT_NODES], sc[BKT_NODES], excl[BKT_NODES], fillb[BKT_NODES];

    const int b = blockIdx.x, t = threadIdx.x;
    const int node0 = b * BKT_NODES;
    const int nb = min(BKT_NODES, N - node0);
    const int base = b * BKT_SLOT;

    int ccnt[NSHARD], cbase[NSHARD];
    int m = 0;
#pragma unroll
    for (int s = 0; s < NSHARD; ++s) {
        int c = fill[(s * NB + b) << 4];
        c = min(c, CELL_CAP);
        ccnt[s] = c;
        cbase[s] = m;
        m += c;
    }
    if (m > BCAP) m = BCAP;   // +22 sigma impossible; avoid corruption

    for (int j = t; j < BKT_NODES; j += 256) { cnt[j] = 0; fillb[j] = 0; }
    __syncthreads();

    for (int i = t; i < m; i += 256) {
        int s = 0;
#pragma unroll
        for (int j = 1; j < NSHARD; ++j) if (i >= cbase[j]) s = j;
        u32 p = bedge[(size_t)(b * NSHARD + s) * CELL_CAP + (i - cbase[s])];
        buf[i] = p;
        atomicAdd(&cnt[p >> 17], 1);
    }
    __syncthreads();   // all bedge reads for this bucket complete here

    if (t < BKT_NODES) sc[t] = cnt[t];
    __syncthreads();
#pragma unroll
    for (int off = 1; off < BKT_NODES; off <<= 1) {
        int u = 0;
        if (t < BKT_NODES && t >= off) u = sc[t - off];
        __syncthreads();
        if (t < BKT_NODES) sc[t] += u;
        __syncthreads();
    }
    if (t < BKT_NODES) {
        int ex = sc[t] - cnt[t];
        excl[t] = ex;
        if (t < nb) {
            row_ptr[node0 + t] = base + ex;
            row_end[node0 + t] = base + sc[t];
            dinv[node0 + t]    = rsqrtf((float)(cnt[t] + 1));   // +1 self-loop
        }
    }
    __syncthreads();

    for (int i = t; i < m; i += 256) {
        u32 p = buf[i];
        int d7 = p >> 17;
        int slot = atomicAdd(&fillb[d7], 1);
        lsrc[excl[d7] + slot] = (int)(p & 0x1FFFF);
    }
    __syncthreads();

    int* csr = (int*)bedge;
    for (int i = t; i < m; i += 256) csr[base + i] = lsrc[i];
}

// ---------------- W split: f32 -> (hi, lo) bf16 ----------------

__global__ void k_split_w(const float* __restrict__ W, u16* __restrict__ Wh,
                          u16* __restrict__ Wl, int n) {
    int i = blockIdx.x * blockDim.x + threadIdx.x;
    if (i < n) {
        float v = W[i];
        u16 h = f2bf(v);
        Wh[i] = h;
        Wl[i] = f2bf(v - bf2f(h));
    }
}

// ---------------- MFMA GEMM body: h = bf16( (A @ W^T) [* dinv] ), node-major output ----
// split-bf16 x3: acc += Ah*Wh + Ah*Wl + Al*Wh (f32 accumulate).

template<int K, int NOUT, bool USE_DINV>
__device__ inline void gemm_body(int bid,
                                 const float* __restrict__ A,
                                 const u16* __restrict__ Wh,
                                 const u16* __restrict__ Wl,
                                 const float* __restrict__ dinv,
                                 u16* __restrict__ h_out,
                                 int M) {
    constexpr int BM = 64, BK = 32, LDT = 40, THREADS = 512;
    constexpr int WAVES_N  = (NOUT == 128) ? 4 : 2;
    constexpr int WAVES_M  = 8 / WAVES_N;
    constexpr int WM       = BM / WAVES_M;
    constexpr int WN       = 32;
    constexpr int MF       = WM / 16;
    constexpr int NF       = WN / 16;

    __shared__ u16 Ah[BM][LDT],   Al[BM][LDT];
    __shared__ u16 Bh[NOUT][LDT], Bl[NOUT][LDT];

    const int t    = threadIdx.x;
    const int lane = t & 63;
    const int wid  = t >> 6;
    const int wm   = (wid / WAVES_N) * WM;
    const int wn   = (wid % WAVES_N) * WN;
    const int lr   = lane & 15;
    const int lk   = (lane >> 4) * 8;
    const int row0 = bid * BM;

    f32x4 acc[MF][NF];
#pragma unroll
    for (int i = 0; i < MF; ++i)
#pragma unroll
        for (int j = 0; j < NF; ++j) acc[i][j] = (f32x4)(0.f);

    for (int k0 = 0; k0 < K; k0 += BK) {
        {
            int r  = t >> 3;
            int c4 = (t & 7) * 4;
            int gr = row0 + r;
            float4 v = make_float4(0.f, 0.f, 0.f, 0.f);
            if (gr < M) v = *(const float4*)&A[(size_t)gr * K + k0 + c4];
            ushort4 hi, lo;
            hi.x = f2bf(v.x); lo.x = f2bf(v.x - bf2f(hi.x));
            hi.y = f2bf(v.y); lo.y = f2bf(v.y - bf2f(hi.y));
            hi.z = f2bf(v.z); lo.z = f2bf(v.z - bf2f(hi.z));
            hi.w = f2bf(v.w); lo.w = f2bf(v.w - bf2f(hi.w));
            *(ushort4*)&Ah[r][c4] = hi;
            *(ushort4*)&Al[r][c4] = lo;
        }
#pragma unroll
        for (int it = 0; it < (NOUT * BK / 4) / THREADS; ++it) {
            int q  = it * THREADS + t;
            int r  = q >> 3;
            int c4 = (q & 7) * 4;
            *(ushort4*)&Bh[r][c4] = *(const ushort4*)&Wh[(size_t)r * K + k0 + c4];
            *(ushort4*)&Bl[r][c4] = *(const ushort4*)&Wl[(size_t)r * K + k0 + c4];
        }
        __syncthreads();

        bf16x8 ah[MF], al[MF], bh[NF], bl[NF];
#pragma unroll
        for (int mf = 0; mf < MF; ++mf) {
            ah[mf] = *(const bf16x8*)&Ah[wm + mf * 16 + lr][lk];
            al[mf] = *(const bf16x8*)&Al[wm + mf * 16 + lr][lk];
        }
#pragma unroll
        for (int nf = 0; nf < NF; ++nf) {
            bh[nf] = *(const bf16x8*)&Bh[wn + nf * 16 + lr][lk];
            bl[nf] = *(const bf16x8*)&Bl[wn + nf * 16 + lr][lk];
        }
#pragma unroll
        for (int mf = 0; mf < MF; ++mf)
#pragma unroll
            for (int nf = 0; nf < NF; ++nf) {
                acc[mf][nf] = __builtin_amdgcn_mfma_f32_16x16x32_bf16(ah[mf], bh[nf], acc[mf][nf], 0, 0, 0);
                acc[mf][nf] = __builtin_amdgcn_mfma_f32_16x16x32_bf16(ah[mf], bl[nf], acc[mf][nf], 0, 0, 0);
                acc[mf][nf] = __builtin_amdgcn_mfma_f32_16x16x32_bf16(al[mf], bh[nf], acc[mf][nf], 0, 0, 0);
            }
        __syncthreads();
    }

#pragma unroll
    for (int mf = 0; mf < MF; ++mf) {
#pragma unroll
        for (int r = 0; r < 4; ++r) {
            int grow = row0 + wm + mf * 16 + (lane >> 4) * 4 + r;
            if (grow < M) {
                float dv = USE_DINV ? dinv[grow] : 1.0f;
#pragma unroll
                for (int nf = 0; nf < NF; ++nf)
                    h_out[(size_t)grow * NOUT + wn + nf * 16 + lr] = f2bf(acc[mf][nf][r] * dv);
            }
        }
    }
}

// fused: groups of 16 blocks = 8 gemm1 + 8 bin, both types on every XCD.
// gemm1 stores RAW h1 (no dinv: dinv not computed yet -> agg1 applies dinv[src]).
__launch_bounds__(512, 4)
__global__ void k_bin_gemm1(const int* __restrict__ esrc, const int* __restrict__ edst,
                            int* __restrict__ fill, u32* __restrict__ bedge,
                            const float* __restrict__ A,
                            const u16* __restrict__ Wh, const u16* __restrict__ Wl,
                            u16* __restrict__ h_out,
                            int E, int NB, int M) {
    int g   = blockIdx.x;
    int vid = ((g >> 4) << 3) | (g & 7);
    if ((g & 15) >= 8) {
        bin_body(vid, g & 7, esrc, edst, fill, bedge, E, NB);
    } else {
        gemm_body<IN_CH, HID, false>(vid, A, Wh, Wl, nullptr, h_out, M);
    }
}

__launch_bounds__(512, 4)
__global__ void k_gemm2(const float* __restrict__ A,
                        const u16* __restrict__ Wh, const u16* __restrict__ Wl,
                        const float* __restrict__ dinv, u16* __restrict__ h_out, int M) {
    gemm_body<HID, LAT, true>(blockIdx.x, A, Wh, Wl, dinv, h_out, M);
}

// ---------------- aggregates (node-major h, 16 B/lane gathers) ----------------

__device__ inline void acc8s(float* a, uint4 v, float d) {
    a[0] = fmaf(__uint_as_float(v.x << 16),          d, a[0]);
    a[1] = fmaf(__uint_as_float(v.x & 0xFFFF0000u),  d, a[1]);
    a[2] = fmaf(__uint_as_float(v.y << 16),          d, a[2]);
    a[3] = fmaf(__uint_as_float(v.y & 0xFFFF0000u),  d, a[3]);
    a[4] = fmaf(__uint_as_float(v.z << 16),          d, a[4]);
    a[5] = fmaf(__uint_as_float(v.z & 0xFFFF0000u),  d, a[5]);
    a[6] = fmaf(__uint_as_float(v.w << 16),          d, a[6]);
    a[7] = fmaf(__uint_as_float(v.w & 0xFFFF0000u),  d, a[7]);
}

// agg1: C=128, h RAW -> apply dinv[src] per edge; out = relu(dinv_i*sum + b), f32 node-major.
// 16 threads/node, 8 channels each.
__global__ void k_agg1(const int* __restrict__ row_ptr, const int* __restrict__ row_end,
                       const int* __restrict__ csr,
                       const u16* __restrict__ h, const float* __restrict__ dinv,
                       const float* __restrict__ bias, float* __restrict__ out, int n) {
    long long tid = (long long)blockIdx.x * blockDim.x + threadIdx.x;
    int node = (int)(tid >> 4);
    if (node >= n) return;
    int c = ((int)tid & 15) * 8;

    int k   = row_ptr[node];
    int end = row_end[node];

    float a[8] = {0.f, 0.f, 0.f, 0.f, 0.f, 0.f, 0.f, 0.f};
    float dvn = dinv[node];
    acc8s(a, *(const uint4*)&h[(size_t)node * HID + c], dvn);   // self-loop: dinv_i * h_raw_i

    for (; k + 4 <= end; k += 4) {                              // 4 gathers in flight
        int s0 = csr[k], s1 = csr[k + 1], s2 = csr[k + 2], s3 = csr[k + 3];
        float d0 = dinv[s0], d1 = dinv[s1], d2 = dinv[s2], d3 = dinv[s3];
        uint4 v0 = *(const uint4*)&h[(size_t)s0 * HID + c];
        uint4 v1 = *(const uint4*)&h[(size_t)s1 * HID + c];
        uint4 v2 = *(const uint4*)&h[(size_t)s2 * HID + c];
        uint4 v3 = *(const uint4*)&h[(size_t)s3 * HID + c];
        acc8s(a, v0, d0); acc8s(a, v1, d1); acc8s(a, v2, d2); acc8s(a, v3, d3);
    }
    for (; k < end; ++k) {
        int s0 = csr[k];
        acc8s(a, *(const uint4*)&h[(size_t)s0 * HID + c], dinv[s0]);
    }

    float4 b0 = *(const float4*)&bias[c];
    float4 b1 = *(const float4*)&bias[c + 4];
    f32x4 o0, o1;
    o0[0] = fmaxf(fmaf(a[0], dvn, b0.x), 0.f);
    o0[1] = fmaxf(fmaf(a[1], dvn, b0.y), 0.f);
    o0[2] = fmaxf(fmaf(a[2], dvn, b0.z), 0.f);
    o0[3] = fmaxf(fmaf(a[3], dvn, b0.w), 0.f);
    o1[0] = fmaxf(fmaf(a[4], dvn, b1.x), 0.f);
    o1[1] = fmaxf(fmaf(a[5], dvn, b1.y), 0.f);
    o1[2] = fmaxf(fmaf(a[6], dvn, b1.z), 0.f);
    o1[3] = fmaxf(fmaf(a[7], dvn, b1.w), 0.f);
    *(f32x4*)&out[(size_t)node * HID + c]     = o0;
    *(f32x4*)&out[(size_t)node * HID + c + 4] = o1;
}

// agg2: C=64, h2 has dinv folded; 8 threads/node, 8 channels each.
__global__ void k_agg2(const int* __restrict__ row_ptr, const int* __restrict__ row_end,
                       const int* __restrict__ csr,
                       const u16* __restrict__ h, const float* __restrict__ dinv,
                       const float* __restrict__ bias, float* __restrict__ out, int n) {
    long long tid = (long long)blockIdx.x * blockDim.x + threadIdx.x;
    int node = (int)(tid >> 3);
    if (node >= n) return;
    int c = ((int)tid & 7) * 8;

    int k   = row_ptr[node];
    int end = row_end[node];

    float a[8] = {0.f, 0.f, 0.f, 0.f, 0.f, 0.f, 0.f, 0.f};
    acc8s(a, *(const uint4*)&h[(size_t)node * LAT + c], 1.0f);   // self-loop term

    for (; k + 4 <= end; k += 4) {
        int s0 = csr[k], s1 = csr[k + 1], s2 = csr[k + 2], s3 = csr[k + 3];
        uint4 v0 = *(const uint4*)&h[(size_t)s0 * LAT + c];
        uint4 v1 = *(const uint4*)&h[(size_t)s1 * LAT + c];
        uint4 v2 = *(const uint4*)&h[(size_t)s2 * LAT + c];
        uint4 v3 = *(const uint4*)&h[(size_t)s3 * LAT + c];
        acc8s(a, v0, 1.0f); acc8s(a, v1, 1.0f); acc8s(a, v2, 1.0f); acc8s(a, v3, 1.0f);
    }
    for (; k < end; ++k) {
        int s0 = csr[k];
        acc8s(a, *(const uint4*)&h[(size_t)s0 * LAT + c], 1.0f);
    }

    float dvn = dinv[node];
    float4 b0 = *(const float4*)&bias[c];
    float4 b1 = *(const float4*)&bias[c + 4];
    f32x4 o0, o1;
    o0[0] = fmaf(a[0], dvn, b0.x);
    o0[1] = fmaf(a[1], dvn, b0.y);
    o0[2] = fmaf(a[2], dvn, b0.z);
    o0[3] = fmaf(a[3], dvn, b0.w);
    o1[0] = fmaf(a[4], dvn, b1.x);
    o1[1] = fmaf(a[5], dvn, b1.y);
    o1[2] = fmaf(a[6], dvn, b1.z);
    o1[3] = fmaf(a[7], dvn, b1.w);
    *(f32x4*)&out[(size_t)node * LAT + c]     = o0;
    *(f32x4*)&out[(size_t)node * LAT + c + 4] = o1;
}

// ---------------- launch ----------------

extern "C" void kernel_launch(void* const* d_in, const int* in_sizes, int n_in,
                              void* d_out, int out_size, void* d_ws, size_t ws_size,
                              hipStream_t stream) {
    const float* x   = (const float*)d_in[0];
    const int*   ei  = (const int*)d_in[1];     // harness delivers integers as int32
    const float* W1  = (const float*)d_in[2];
    const float* b1  = (const float*)d_in[3];
    const float* W2  = (const float*)d_in[4];
    const float* b2  = (const float*)d_in[5];
    float*       out = (float*)d_out;

    const int N = in_sizes[0] / IN_CH;
    const int E = in_sizes[1] / 2;
    const int* esrc = ei;
    const int* edst = ei + E;

    const int NB = (N + BKT_NODES - 1) / BKT_NODES;   // buckets

    char* ws = (char*)d_ws;
    int*   fill    = (int*)ws;    ws += (size_t)NB * NSHARD * 16 * 4;  // line-padded counters
    u32*   bedge   = (u32*)ws;    ws += (size_t)NB * BKT_SLOT * 4;     // slotted edges; csr in place
    int*   row_ptr = (int*)ws;    ws += (size_t)N * 4;
    int*   row_end = (int*)ws;    ws += (size_t)N * 4;
    float* dinv    = (float*)ws;  ws += (size_t)N * 4;
    u16*   W1h     = (u16*)ws;    ws += (size_t)HID * IN_CH * 2;
    u16*   W1l     = (u16*)ws;    ws += (size_t)HID * IN_CH * 2;
    u16*   W2h     = (u16*)ws;    ws += (size_t)LAT * HID * 2;
    u16*   W2l     = (u16*)ws;    ws += (size_t)LAT * HID * 2;
    u16*   h1      = (u16*)ws;    ws += (size_t)N * HID * 2;   // node-major bf16 (RAW, layer 1)
    u16*   h2      = (u16*)ws;    ws += (size_t)N * LAT * 2;   // node-major bf16 (layer 2, *dinv)
    float* out1    = (float*)ws;  ws += (size_t)N * HID * 4;   // agg1 output (f32, GEMM2's A)
    const int* csr_src = (const int*)bedge;                    // aliased (bsort flushes in place)

    dim3 blk(256);

    const int GB = (N + 63) / 64;                 // gemm1 blocks
    const int BB = (E + 1023) / 1024;             // bin blocks
    const int NG = (max(GB, BB) + 7) / 8;         // 16-block groups (8 gemm + 8 bin)

    // ---- prep ----
    k_zero   <<<(NB * NSHARD * 16 + 255) / 256, blk, 0, stream>>>(fill, NB * NSHARD * 16);
    k_split_w<<<(HID * IN_CH + 255) / 256, blk, 0, stream>>>(W1, W1h, W1l, HID * IN_CH);
    k_split_w<<<(LAT * HID + 255) / 256, blk, 0, stream>>>(W2, W2h, W2l, LAT * HID);

    // ---- fused: edge binning (latency-bound) || gemm1 (MFMA-bound) ----
    k_bin_gemm1<<<NG * 16, dim3(512), 0, stream>>>(esrc, edst, fill, bedge,
                                                   x, W1h, W1l, h1, E, NB, N);

    // ---- CSR finalize (counting sort in LDS) ----
    k_bsort<<<NB, blk, 0, stream>>>(fill, bedge, row_ptr, row_end, dinv, N, NB);

    // ---- layer 1 aggregate (node-major gathers; applies dinv[src] and dinv[node]) ----
    {
        long long tot = (long long)N * 16;
        k_agg1<<<(unsigned)((tot + 255) / 256), blk, 0, stream>>>(
            row_ptr, row_end, csr_src, h1, dinv, b1, out1, N);
    }

    // ---- layer 2 ----
    k_gemm2<<<GB, dim3(512), 0, stream>>>(out1, W2h, W2l, dinv, h2, N);
    {
        long long tot = (long long)N * 8;
        k_agg2<<<(unsigned)((tot + 255) / 256), blk, 0, stream>>>(
            row_ptr, row_end, csr_src, h2, dinv, b2, out, N);
    }
}

// Round 12
// 203.738 us; speedup vs baseline: 2.1997x; 1.0437x over previous
//
#include <hip/hip_runtime.h>
#include <math.h>

constexpr int IN_CH = 256;
constexpr int HID   = 128;
constexpr int LAT   = 64;

constexpr int SBN    = 1024;    // nodes per super-bucket
constexpr int SB_CAP = 18432;   // edges per SB region: mean 16384, +16 sigma
constexpr int EPB    = 8192;    // edges per bin block
constexpr int HCAP   = 9472;    // per-half-SB LDS staging: mean 8192, +14 sigma

typedef unsigned short u16;
typedef unsigned int   u32;
typedef unsigned char  u8;
typedef __bf16  bf16x8 __attribute__((ext_vector_type(8)));
typedef float   f32x4  __attribute__((ext_vector_type(4)));

__device__ inline u16 f2bf(float f) {
    unsigned u = __float_as_uint(f);
    unsigned r = u + 0x7FFF + ((u >> 16) & 1);
    return (u16)(r >> 16);
}
__device__ inline float bf2f(u16 h) {
    return __uint_as_float((unsigned)h << 16);
}

// ---------------- coalesced-write CSR build ----------------

__global__ void k_zero(int* p, int n) {
    int i = blockIdx.x * blockDim.x + threadIdx.x;
    if (i < n) p[i] = 0;
}

// stage 1: per-block LDS counting sort by super-bucket, then COALESCED run flush.
// payload = src | (d & 1023) << 17  (27 bits).
__launch_bounds__(512)
__global__ void k_bin_sb(const int* __restrict__ esrc, const int* __restrict__ edst,
                         int* __restrict__ sb_fill, u32* __restrict__ sbe,
                         int E, int NSB) {
    __shared__ u32 sorted[EPB];      // 32 KB
    __shared__ u8  ssb[EPB];         // 8 KB
    __shared__ int cnt[128], sc[128], excl[128], fil[128], off[128];

    const int t  = threadIdx.x;
    const int e0 = blockIdx.x * EPB;

    for (int j = t; j < 128; j += 512) { cnt[j] = 0; fil[j] = 0; }
    __syncthreads();

    // pass 1: count per SB
#pragma unroll
    for (int it = 0; it < EPB / 512; ++it) {
        int e = e0 + it * 512 + t;
        if (e < E) atomicAdd(&cnt[edst[e] >> 10], 1);
    }
    __syncthreads();

    // scan 128 (Hillis-Steele)
    if (t < 128) sc[t] = cnt[t];
    __syncthreads();
#pragma unroll
    for (int o = 1; o < 128; o <<= 1) {
        int u = 0;
        if (t < 128 && t >= o) u = sc[t - o];
        __syncthreads();
        if (t < 128) sc[t] += u;
        __syncthreads();
    }
    if (t < 128) excl[t] = sc[t] - cnt[t];
    // reserve global space per SB (one atomic per (block,SB))
    if (t < NSB) off[t] = atomicAdd(&sb_fill[t], cnt[t]);
    __syncthreads();

    // pass 2: re-read edges, scatter into LDS sorted order
#pragma unroll
    for (int it = 0; it < EPB / 512; ++it) {
        int e = e0 + it * 512 + t;
        if (e < E) {
            int d  = edst[e];
            int sb = d >> 10;
            int pos = excl[sb] + atomicAdd(&fil[sb], 1);
            sorted[pos] = (u32)esrc[e] | ((u32)(d & 1023) << 17);
            ssb[pos]    = (u8)sb;
        }
    }
    __syncthreads();

    // coalesced run flush: consecutive i -> consecutive global addresses within a run
    int mtot = sc[127];
    for (int i = t; i < mtot; i += 512) {
        int sb = ssb[i];
        int o  = off[sb] + (i - excl[sb]);
        if (o < SB_CAP) sbe[(size_t)sb * SB_CAP + o] = sorted[i];
    }
}

// stage 2: per-half-SB counting sort; two streamed passes over the SB region,
// LDS staging, coalesced csr flush. Emits row_ptr/row_end/dinv.
__launch_bounds__(512)
__global__ void k_sbsort(const int* __restrict__ sb_fill, const u32* __restrict__ sbe,
                         int* __restrict__ csr, int* __restrict__ row_ptr,
                         int* __restrict__ row_end, float* __restrict__ dinv, int N) {
    __shared__ int cnt[SBN];         // 4 KB
    __shared__ int exclh[512];       // 2 KB (excl for my half's nodes)
    __shared__ int fillb[512];       // 2 KB
    __shared__ int lsrc[HCAP];       // 37 KB
    __shared__ int wsum[8];
    __shared__ int sh_h1base, sh_mtot;

    const int t    = threadIdx.x;
    const int sb   = blockIdx.x >> 1;
    const int half = blockIdx.x & 1;
    const int m    = min(sb_fill[sb], SB_CAP);
    const size_t base = (size_t)sb * SB_CAP;
    const int node0 = sb * SBN;

    for (int j = t; j < SBN; j += 512) cnt[j] = 0;
    fillb[t & 511] = 0;
    __syncthreads();

    // pass 1: count all 1024 nodes of this SB
    for (int i = t; i < m; i += 512)
        atomicAdd(&cnt[sbe[base + i] >> 17], 1);
    __syncthreads();

    // scan 1024 via pair-sum + 512-thread block scan
    int c0 = cnt[2 * t], c1 = cnt[2 * t + 1];
    int p  = c0 + c1;
    int lane = t & 63, wid = t >> 6;
    int v = p;
#pragma unroll
    for (int o = 1; o < 64; o <<= 1) {
        int u = __shfl_up(v, o, 64);
        if (lane >= o) v += u;
    }
    if (lane == 63) wsum[wid] = v;
    __syncthreads();
    int woff = 0;
#pragma unroll
    for (int w = 0; w < 8; ++w) if (w < wid) woff += wsum[w];
    int incl = woff + v;          // inclusive over pairs
    int eP   = incl - p;          // exclusive pair offset
    if (t == 511) sh_mtot = incl;
    if (t == 256) sh_h1base = eP; // excl at node 512

#pragma unroll
    for (int q = 0; q < 2; ++q) {
        int j  = 2 * t + q;
        int ex = q ? (eP + c0) : eP;
        int cc = q ? c1 : c0;
        if ((j >> 9) == half) {
            exclh[j & 511] = ex;
            int node = node0 + j;
            if (node < N) {
                row_ptr[node] = (int)base + ex;
                row_end[node] = (int)base + ex + cc;
                dinv[node]    = rsqrtf((float)(cc + 1));   // +1 self-loop
            }
        }
    }
    __syncthreads();

    const int hb   = (half == 0) ? 0 : sh_h1base;
    int mh = (half == 0) ? sh_h1base : (sh_mtot - sh_h1base);

    // pass 2: stage my half into LDS
    for (int i = t; i < m; i += 512) {
        u32 p2  = sbe[base + i];
        int d10 = p2 >> 17;
        if ((d10 >> 9) == half) {
            int slot = atomicAdd(&fillb[d10 & 511], 1);
            int pos  = exclh[d10 & 511] - hb + slot;
            if (pos < HCAP) lsrc[pos] = (int)(p2 & 0x1FFFF);
        }
    }
    __syncthreads();

    if (mh > HCAP) mh = HCAP;
    for (int i = t; i < mh; i += 512) csr[base + hb + i] = lsrc[i];   // coalesced
}

// ---------------- W split: f32 -> (hi, lo) bf16 ----------------

__global__ void k_split_w(const float* __restrict__ W, u16* __restrict__ Wh,
                          u16* __restrict__ Wl, int n) {
    int i = blockIdx.x * blockDim.x + threadIdx.x;
    if (i < n) {
        float v = W[i];
        u16 h = f2bf(v);
        Wh[i] = h;
        Wl[i] = f2bf(v - bf2f(h));
    }
}

// ---------------- MFMA GEMM: h = bf16( (A @ W^T) * dinv[row] ), node-major ----------------
// split-bf16 x3: acc += Ah*Wh + Ah*Wl + Al*Wh (f32 accumulate).
// BM=64, BK=32, 512 threads = 8 waves.

template<int K, int NOUT>
__device__ inline void gemm_body(int bid,
                                 const float* __restrict__ A,
                                 const u16* __restrict__ Wh,
                                 const u16* __restrict__ Wl,
                                 const float* __restrict__ dinv,
                                 u16* __restrict__ h_out,
                                 int M) {
    constexpr int BM = 64, BK = 32, LDT = 40, THREADS = 512;
    constexpr int WAVES_N  = (NOUT == 128) ? 4 : 2;
    constexpr int WAVES_M  = 8 / WAVES_N;
    constexpr int WM       = BM / WAVES_M;
    constexpr int WN       = 32;
    constexpr int MF       = WM / 16;
    constexpr int NF       = WN / 16;

    __shared__ u16 Ah[BM][LDT],   Al[BM][LDT];
    __shared__ u16 Bh[NOUT][LDT], Bl[NOUT][LDT];

    const int t    = threadIdx.x;
    const int lane = t & 63;
    const int wid  = t >> 6;
    const int wm   = (wid / WAVES_N) * WM;
    const int wn   = (wid % WAVES_N) * WN;
    const int lr   = lane & 15;
    const int lk   = (lane >> 4) * 8;
    const int row0 = bid * BM;

    f32x4 acc[MF][NF];
#pragma unroll
    for (int i = 0; i < MF; ++i)
#pragma unroll
        for (int j = 0; j < NF; ++j) acc[i][j] = (f32x4)(0.f);

    for (int k0 = 0; k0 < K; k0 += BK) {
        {
            int r  = t >> 3;
            int c4 = (t & 7) * 4;
            int gr = row0 + r;
            float4 v = make_float4(0.f, 0.f, 0.f, 0.f);
            if (gr < M) v = *(const float4*)&A[(size_t)gr * K + k0 + c4];
            ushort4 hi, lo;
            hi.x = f2bf(v.x); lo.x = f2bf(v.x - bf2f(hi.x));
            hi.y = f2bf(v.y); lo.y = f2bf(v.y - bf2f(hi.y));
            hi.z = f2bf(v.z); lo.z = f2bf(v.z - bf2f(hi.z));
            hi.w = f2bf(v.w); lo.w = f2bf(v.w - bf2f(hi.w));
            *(ushort4*)&Ah[r][c4] = hi;
            *(ushort4*)&Al[r][c4] = lo;
        }
#pragma unroll
        for (int it = 0; it < (NOUT * BK / 4) / THREADS; ++it) {
            int q  = it * THREADS + t;
            int r  = q >> 3;
            int c4 = (q & 7) * 4;
            *(ushort4*)&Bh[r][c4] = *(const ushort4*)&Wh[(size_t)r * K + k0 + c4];
            *(ushort4*)&Bl[r][c4] = *(const ushort4*)&Wl[(size_t)r * K + k0 + c4];
        }
        __syncthreads();

        bf16x8 ah[MF], al[MF], bh[NF], bl[NF];
#pragma unroll
        for (int mf = 0; mf < MF; ++mf) {
            ah[mf] = *(const bf16x8*)&Ah[wm + mf * 16 + lr][lk];
            al[mf] = *(const bf16x8*)&Al[wm + mf * 16 + lr][lk];
        }
#pragma unroll
        for (int nf = 0; nf < NF; ++nf) {
            bh[nf] = *(const bf16x8*)&Bh[wn + nf * 16 + lr][lk];
            bl[nf] = *(const bf16x8*)&Bl[wn + nf * 16 + lr][lk];
        }
#pragma unroll
        for (int mf = 0; mf < MF; ++mf)
#pragma unroll
            for (int nf = 0; nf < NF; ++nf) {
                acc[mf][nf] = __builtin_amdgcn_mfma_f32_16x16x32_bf16(ah[mf], bh[nf], acc[mf][nf], 0, 0, 0);
                acc[mf][nf] = __builtin_amdgcn_mfma_f32_16x16x32_bf16(ah[mf], bl[nf], acc[mf][nf], 0, 0, 0);
                acc[mf][nf] = __builtin_amdgcn_mfma_f32_16x16x32_bf16(al[mf], bh[nf], acc[mf][nf], 0, 0, 0);
            }
        __syncthreads();
    }

#pragma unroll
    for (int mf = 0; mf < MF; ++mf) {
#pragma unroll
        for (int r = 0; r < 4; ++r) {
            int grow = row0 + wm + mf * 16 + (lane >> 4) * 4 + r;
            if (grow < M) {
                float dv = dinv[grow];
#pragma unroll
                for (int nf = 0; nf < NF; ++nf)
                    h_out[(size_t)grow * NOUT + wn + nf * 16 + lr] = f2bf(acc[mf][nf][r] * dv);
            }
        }
    }
}

__launch_bounds__(512, 4)
__global__ void k_gemm1(const float* __restrict__ A,
                        const u16* __restrict__ Wh, const u16* __restrict__ Wl,
                        const float* __restrict__ dinv, u16* __restrict__ h_out, int M) {
    gemm_body<IN_CH, HID>(blockIdx.x, A, Wh, Wl, dinv, h_out, M);
}

__launch_bounds__(512, 4)
__global__ void k_gemm2(const float* __restrict__ A,
                        const u16* __restrict__ Wh, const u16* __restrict__ Wl,
                        const float* __restrict__ dinv, u16* __restrict__ h_out, int M) {
    gemm_body<HID, LAT>(blockIdx.x, A, Wh, Wl, dinv, h_out, M);
}

// ---------------- aggregates (node-major bf16 h, 16 B/lane gathers) ----------------

__device__ inline void acc8(float* a, uint4 v) {
    a[0] += __uint_as_float(v.x << 16);
    a[1] += __uint_as_float(v.x & 0xFFFF0000u);
    a[2] += __uint_as_float(v.y << 16);
    a[3] += __uint_as_float(v.y & 0xFFFF0000u);
    a[4] += __uint_as_float(v.z << 16);
    a[5] += __uint_as_float(v.z & 0xFFFF0000u);
    a[6] += __uint_as_float(v.w << 16);
    a[7] += __uint_as_float(v.w & 0xFFFF0000u);
}

template<int C, bool RELU>
__global__ void k_aggregate(const int* __restrict__ row_ptr,
                            const int* __restrict__ row_end,
                            const int* __restrict__ csr,
                            const u16* __restrict__ h,
                            const float* __restrict__ dinv,
                            const float* __restrict__ bias,
                            float* __restrict__ out, int n) {
    constexpr int QSHIFT = (C == 128) ? 4 : 3;     // C/8 threads per node
    long long tid = (long long)blockIdx.x * blockDim.x + threadIdx.x;
    int node = (int)(tid >> QSHIFT);
    if (node >= n) return;
    int c = ((int)tid & ((1 << QSHIFT) - 1)) * 8;

    int k   = row_ptr[node];
    int end = row_end[node];

    float a[8] = {0.f, 0.f, 0.f, 0.f, 0.f, 0.f, 0.f, 0.f};
    acc8(a, *(const uint4*)&h[(size_t)node * C + c]);    // self-loop term

    for (; k + 4 <= end; k += 4) {                        // 4 gathers in flight
        int s0 = csr[k], s1 = csr[k + 1], s2 = csr[k + 2], s3 = csr[k + 3];
        uint4 v0 = *(const uint4*)&h[(size_t)s0 * C + c];
        uint4 v1 = *(const uint4*)&h[(size_t)s1 * C + c];
        uint4 v2 = *(const uint4*)&h[(size_t)s2 * C + c];
        uint4 v3 = *(const uint4*)&h[(size_t)s3 * C + c];
        acc8(a, v0); acc8(a, v1); acc8(a, v2); acc8(a, v3);
    }
    for (; k < end; ++k) {
        int s0 = csr[k];
        acc8(a, *(const uint4*)&h[(size_t)s0 * C + c]);
    }

    float dvn = dinv[node];
    float4 b0 = *(const float4*)&bias[c];
    float4 b1 = *(const float4*)&bias[c + 4];
    f32x4 o0, o1;
    o0[0] = fmaf(a[0], dvn, b0.x);
    o0[1] = fmaf(a[1], dvn, b0.y);
    o0[2] = fmaf(a[2], dvn, b0.z);
    o0[3] = fmaf(a[3], dvn, b0.w);
    o1[0] = fmaf(a[4], dvn, b1.x);
    o1[1] = fmaf(a[5], dvn, b1.y);
    o1[2] = fmaf(a[6], dvn, b1.z);
    o1[3] = fmaf(a[7], dvn, b1.w);
    if (RELU) {
        o0[0] = fmaxf(o0[0], 0.f); o0[1] = fmaxf(o0[1], 0.f);
        o0[2] = fmaxf(o0[2], 0.f); o0[3] = fmaxf(o0[3], 0.f);
        o1[0] = fmaxf(o1[0], 0.f); o1[1] = fmaxf(o1[1], 0.f);
        o1[2] = fmaxf(o1[2], 0.f); o1[3] = fmaxf(o1[3], 0.f);
    }
    *(f32x4*)&out[(size_t)node * C + c]     = o0;
    *(f32x4*)&out[(size_t)node * C + c + 4] = o1;
}

// ---------------- launch ----------------

extern "C" void kernel_launch(void* const* d_in, const int* in_sizes, int n_in,
                              void* d_out, int out_size, void* d_ws, size_t ws_size,
                              hipStream_t stream) {
    const float* x   = (const float*)d_in[0];
    const int*   ei  = (const int*)d_in[1];     // harness delivers integers as int32
    const float* W1  = (const float*)d_in[2];
    const float* b1  = (const float*)d_in[3];
    const float* W2  = (const float*)d_in[4];
    const float* b2  = (const float*)d_in[5];
    float*       out = (float*)d_out;

    const int N = in_sizes[0] / IN_CH;
    const int E = in_sizes[1] / 2;
    const int* esrc = ei;
    const int* edst = ei + E;

    const int NSB = (N + SBN - 1) / SBN;   // super-buckets (98)
    const int NBB = (E + EPB - 1) / EPB;   // bin blocks (196)
    const int GB  = (N + 63) / 64;         // gemm blocks

    char* ws = (char*)d_ws;
    int*   sb_fill = (int*)ws;    ws += (size_t)((NSB + 31) & ~31) * 4;
    u32*   sbe     = (u32*)ws;    ws += (size_t)NSB * SB_CAP * 4;   // SB-grouped edges
    int*   csr     = (int*)ws;    ws += (size_t)NSB * SB_CAP * 4;   // slotted CSR
    int*   row_ptr = (int*)ws;    ws += (size_t)N * 4;
    int*   row_end = (int*)ws;    ws += (size_t)N * 4;
    float* dinv    = (float*)ws;  ws += (size_t)N * 4;
    u16*   W1h     = (u16*)ws;    ws += (size_t)HID * IN_CH * 2;
    u16*   W1l     = (u16*)ws;    ws += (size_t)HID * IN_CH * 2;
    u16*   W2h     = (u16*)ws;    ws += (size_t)LAT * HID * 2;
    u16*   W2l     = (u16*)ws;    ws += (size_t)LAT * HID * 2;
    u16*   h1      = (u16*)ws;    ws += (size_t)N * HID * 2;   // bf16, dinv folded
    u16*   h2      = (u16*)ws;    ws += (size_t)N * LAT * 2;   // bf16, dinv folded
    float* out1    = (float*)ws;  ws += (size_t)N * HID * 4;   // agg1 out (f32, GEMM2's A)

    dim3 blk(256);

    // ---- prep ----
    k_zero   <<<1, 128, 0, stream>>>(sb_fill, NSB);
    k_split_w<<<(HID * IN_CH + 255) / 256, blk, 0, stream>>>(W1, W1h, W1l, HID * IN_CH);
    k_split_w<<<(LAT * HID + 255) / 256, blk, 0, stream>>>(W2, W2h, W2l, LAT * HID);

    // ---- coalesced-write CSR build ----
    k_bin_sb<<<NBB, dim3(512), 0, stream>>>(esrc, edst, sb_fill, sbe, E, NSB);
    k_sbsort<<<NSB * 2, dim3(512), 0, stream>>>(sb_fill, sbe, csr, row_ptr, row_end, dinv, N);

    // ---- layer 1: 256 -> 128, relu ----
    k_gemm1<<<GB, dim3(512), 0, stream>>>(x, W1h, W1l, dinv, h1, N);
    {
        long long tot = (long long)N * 16;
        k_aggregate<HID, true><<<(unsigned)((tot + 255) / 256), blk, 0, stream>>>(
            row_ptr, row_end, csr, h1, dinv, b1, out1, N);
    }

    // ---- layer 2: 128 -> 64 ----
    k_gemm2<<<GB, dim3(512), 0, stream>>>(out1, W2h, W2l, dinv, h2, N);
    {
        long long tot = (long long)N * 8;
        k_aggregate<LAT, false><<<(unsigned)((tot + 255) / 256), blk, 0, stream>>>(
            row_ptr, row_end, csr, h2, dinv, b2, out, N);
    }
}

// Round 13
// 197.615 us; speedup vs baseline: 2.2678x; 1.0310x over previous
//
#include <hip/hip_runtime.h>
#include <math.h>

constexpr int IN_CH = 256;
constexpr int HID   = 128;
constexpr int LAT   = 64;

constexpr int SBN    = 1024;    // nodes per super-bucket
constexpr int SB_CAP = 18432;   // edges per SB region: mean 16384, +16 sigma
constexpr int EPB    = 8192;    // edges per bin block
constexpr int HCAP   = 9472;    // per-half-SB LDS staging: mean 8192, +14 sigma

typedef unsigned short u16;
typedef unsigned int   u32;
typedef unsigned char  u8;
typedef __bf16  bf16x8 __attribute__((ext_vector_type(8)));
typedef float   f32x4  __attribute__((ext_vector_type(4)));

__device__ inline u16 f2bf(float f) {
    unsigned u = __float_as_uint(f);
    unsigned r = u + 0x7FFF + ((u >> 16) & 1);
    return (u16)(r >> 16);
}
__device__ inline float bf2f(u16 h) {
    return __uint_as_float((unsigned)h << 16);
}

// ---------------- coalesced-write CSR build ----------------

__global__ void k_zero(int* p, int n) {
    int i = blockIdx.x * blockDim.x + threadIdx.x;
    if (i < n) p[i] = 0;
}

// stage 1: per-block LDS counting sort by super-bucket, then COALESCED run flush.
__launch_bounds__(512)
__global__ void k_bin_sb(const int* __restrict__ esrc, const int* __restrict__ edst,
                         int* __restrict__ sb_fill, u32* __restrict__ sbe,
                         int E, int NSB) {
    __shared__ u32 sorted[EPB];      // 32 KB
    __shared__ u8  ssb[EPB];         // 8 KB
    __shared__ int cnt[128], sc[128], excl[128], fil[128], off[128];

    const int t  = threadIdx.x;
    const int e0 = blockIdx.x * EPB;

    for (int j = t; j < 128; j += 512) { cnt[j] = 0; fil[j] = 0; }
    __syncthreads();

#pragma unroll
    for (int it = 0; it < EPB / 512; ++it) {
        int e = e0 + it * 512 + t;
        if (e < E) atomicAdd(&cnt[edst[e] >> 10], 1);
    }
    __syncthreads();

    if (t < 128) sc[t] = cnt[t];
    __syncthreads();
#pragma unroll
    for (int o = 1; o < 128; o <<= 1) {
        int u = 0;
        if (t < 128 && t >= o) u = sc[t - o];
        __syncthreads();
        if (t < 128) sc[t] += u;
        __syncthreads();
    }
    if (t < 128) excl[t] = sc[t] - cnt[t];
    if (t < NSB) off[t] = atomicAdd(&sb_fill[t], cnt[t]);
    __syncthreads();

#pragma unroll
    for (int it = 0; it < EPB / 512; ++it) {
        int e = e0 + it * 512 + t;
        if (e < E) {
            int d  = edst[e];
            int sb = d >> 10;
            int pos = excl[sb] + atomicAdd(&fil[sb], 1);
            sorted[pos] = (u32)esrc[e] | ((u32)(d & 1023) << 17);
            ssb[pos]    = (u8)sb;
        }
    }
    __syncthreads();

    int mtot = sc[127];
    for (int i = t; i < mtot; i += 512) {
        int sb = ssb[i];
        int o  = off[sb] + (i - excl[sb]);
        if (o < SB_CAP) sbe[(size_t)sb * SB_CAP + o] = sorted[i];
    }
}

// stage 2: per-half-SB counting sort; streamed passes, LDS staging, coalesced flush.
__launch_bounds__(512)
__global__ void k_sbsort(const int* __restrict__ sb_fill, const u32* __restrict__ sbe,
                         int* __restrict__ csr, int* __restrict__ row_ptr,
                         int* __restrict__ row_end, float* __restrict__ dinv, int N) {
    __shared__ int cnt[SBN];
    __shared__ int exclh[512];
    __shared__ int fillb[512];
    __shared__ int lsrc[HCAP];
    __shared__ int wsum[8];
    __shared__ int sh_h1base, sh_mtot;

    const int t    = threadIdx.x;
    const int sb   = blockIdx.x >> 1;
    const int half = blockIdx.x & 1;
    const int m    = min(sb_fill[sb], SB_CAP);
    const size_t base = (size_t)sb * SB_CAP;
    const int node0 = sb * SBN;

    for (int j = t; j < SBN; j += 512) cnt[j] = 0;
    fillb[t & 511] = 0;
    __syncthreads();

    for (int i = t; i < m; i += 512)
        atomicAdd(&cnt[sbe[base + i] >> 17], 1);
    __syncthreads();

    int c0 = cnt[2 * t], c1 = cnt[2 * t + 1];
    int p  = c0 + c1;
    int lane = t & 63, wid = t >> 6;
    int v = p;
#pragma unroll
    for (int o = 1; o < 64; o <<= 1) {
        int u = __shfl_up(v, o, 64);
        if (lane >= o) v += u;
    }
    if (lane == 63) wsum[wid] = v;
    __syncthreads();
    int woff = 0;
#pragma unroll
    for (int w = 0; w < 8; ++w) if (w < wid) woff += wsum[w];
    int incl = woff + v;
    int eP   = incl - p;
    if (t == 511) sh_mtot = incl;
    if (t == 256) sh_h1base = eP;

#pragma unroll
    for (int q = 0; q < 2; ++q) {
        int j  = 2 * t + q;
        int ex = q ? (eP + c0) : eP;
        int cc = q ? c1 : c0;
        if ((j >> 9) == half) {
            exclh[j & 511] = ex;
            int node = node0 + j;
            if (node < N) {
                row_ptr[node] = (int)base + ex;
                row_end[node] = (int)base + ex + cc;
                dinv[node]    = rsqrtf((float)(cc + 1));   // +1 self-loop
            }
        }
    }
    __syncthreads();

    const int hb = (half == 0) ? 0 : sh_h1base;
    int mh = (half == 0) ? sh_h1base : (sh_mtot - sh_h1base);

    for (int i = t; i < m; i += 512) {
        u32 p2  = sbe[base + i];
        int d10 = p2 >> 17;
        if ((d10 >> 9) == half) {
            int slot = atomicAdd(&fillb[d10 & 511], 1);
            int pos  = exclh[d10 & 511] - hb + slot;
            if (pos < HCAP) lsrc[pos] = (int)(p2 & 0x1FFFF);
        }
    }
    __syncthreads();

    if (mh > HCAP) mh = HCAP;
    for (int i = t; i < mh; i += 512) csr[base + hb + i] = lsrc[i];
}

// ---------------- W split: f32 -> (hi, lo) bf16 ----------------

__global__ void k_split_w(const float* __restrict__ W, u16* __restrict__ Wh,
                          u16* __restrict__ Wl, int n) {
    int i = blockIdx.x * blockDim.x + threadIdx.x;
    if (i < n) {
        float v = W[i];
        u16 h = f2bf(v);
        Wh[i] = h;
        Wl[i] = f2bf(v - bf2f(h));
    }
}

// ---------------- MFMA GEMM: h = bf16( (A @ W^T) * dinv[row] ), node-major ----------------
// A_BF16=false: A is f32, split x3 (Ah*Wh + Ah*Wl + Al*Wh).
// A_BF16=true:  A is bf16, x2 (Ah*Wh + Ah*Wl).

template<int K, int NOUT, bool A_BF16, typename AT>
__device__ inline void gemm_body(int bid,
                                 const AT* __restrict__ A,
                                 const u16* __restrict__ Wh,
                                 const u16* __restrict__ Wl,
                                 const float* __restrict__ dinv,
                                 u16* __restrict__ h_out,
                                 int M) {
    constexpr int BM = 64, BK = 32, LDT = 40, THREADS = 512;
    constexpr int WAVES_N  = (NOUT == 128) ? 4 : 2;
    constexpr int WAVES_M  = 8 / WAVES_N;
    constexpr int WM       = BM / WAVES_M;
    constexpr int WN       = 32;
    constexpr int MF       = WM / 16;
    constexpr int NF       = WN / 16;

    __shared__ u16 Ah[BM][LDT];
    __shared__ u16 Al[A_BF16 ? 1 : BM][A_BF16 ? 1 : LDT];
    __shared__ u16 Bh[NOUT][LDT], Bl[NOUT][LDT];

    const int t    = threadIdx.x;
    const int lane = t & 63;
    const int wid  = t >> 6;
    const int wm   = (wid / WAVES_N) * WM;
    const int wn   = (wid % WAVES_N) * WN;
    const int lr   = lane & 15;
    const int lk   = (lane >> 4) * 8;
    const int row0 = bid * BM;

    f32x4 acc[MF][NF];
#pragma unroll
    for (int i = 0; i < MF; ++i)
#pragma unroll
        for (int j = 0; j < NF; ++j) acc[i][j] = (f32x4)(0.f);

    for (int k0 = 0; k0 < K; k0 += BK) {
        {
            int r  = t >> 3;
            int c4 = (t & 7) * 4;
            int gr = row0 + r;
            if (A_BF16) {
                ushort4 hv = make_ushort4(0, 0, 0, 0);
                if (gr < M) hv = *(const ushort4*)&((const u16*)A)[(size_t)gr * K + k0 + c4];
                *(ushort4*)&Ah[r][c4] = hv;
            } else {
                float4 v = make_float4(0.f, 0.f, 0.f, 0.f);
                if (gr < M) v = *(const float4*)&((const float*)A)[(size_t)gr * K + k0 + c4];
                ushort4 hi, lo;
                hi.x = f2bf(v.x); lo.x = f2bf(v.x - bf2f(hi.x));
                hi.y = f2bf(v.y); lo.y = f2bf(v.y - bf2f(hi.y));
                hi.z = f2bf(v.z); lo.z = f2bf(v.z - bf2f(hi.z));
                hi.w = f2bf(v.w); lo.w = f2bf(v.w - bf2f(hi.w));
                *(ushort4*)&Ah[r][c4] = hi;
                *(ushort4*)&Al[r][c4] = lo;
            }
        }
#pragma unroll
        for (int it = 0; it < (NOUT * BK / 4) / THREADS; ++it) {
            int q  = it * THREADS + t;
            int r  = q >> 3;
            int c4 = (q & 7) * 4;
            *(ushort4*)&Bh[r][c4] = *(const ushort4*)&Wh[(size_t)r * K + k0 + c4];
            *(ushort4*)&Bl[r][c4] = *(const ushort4*)&Wl[(size_t)r * K + k0 + c4];
        }
        __syncthreads();

        bf16x8 ah[MF], al[MF], bh[NF], bl[NF];
#pragma unroll
        for (int mf = 0; mf < MF; ++mf) {
            ah[mf] = *(const bf16x8*)&Ah[wm + mf * 16 + lr][lk];
            if (!A_BF16) al[mf] = *(const bf16x8*)&Al[wm + mf * 16 + lr][lk];
        }
#pragma unroll
        for (int nf = 0; nf < NF; ++nf) {
            bh[nf] = *(const bf16x8*)&Bh[wn + nf * 16 + lr][lk];
            bl[nf] = *(const bf16x8*)&Bl[wn + nf * 16 + lr][lk];
        }
#pragma unroll
        for (int mf = 0; mf < MF; ++mf)
#pragma unroll
            for (int nf = 0; nf < NF; ++nf) {
                acc[mf][nf] = __builtin_amdgcn_mfma_f32_16x16x32_bf16(ah[mf], bh[nf], acc[mf][nf], 0, 0, 0);
                acc[mf][nf] = __builtin_amdgcn_mfma_f32_16x16x32_bf16(ah[mf], bl[nf], acc[mf][nf], 0, 0, 0);
                if (!A_BF16)
                    acc[mf][nf] = __builtin_amdgcn_mfma_f32_16x16x32_bf16(al[mf], bh[nf], acc[mf][nf], 0, 0, 0);
            }
        __syncthreads();
    }

#pragma unroll
    for (int mf = 0; mf < MF; ++mf) {
#pragma unroll
        for (int r = 0; r < 4; ++r) {
            int grow = row0 + wm + mf * 16 + (lane >> 4) * 4 + r;
            if (grow < M) {
                float dv = dinv[grow];
#pragma unroll
                for (int nf = 0; nf < NF; ++nf)
                    h_out[(size_t)grow * NOUT + wn + nf * 16 + lr] = f2bf(acc[mf][nf][r] * dv);
            }
        }
    }
}

__launch_bounds__(512, 4)
__global__ void k_gemm1(const float* __restrict__ A,
                        const u16* __restrict__ Wh, const u16* __restrict__ Wl,
                        const float* __restrict__ dinv, u16* __restrict__ h_out, int M) {
    gemm_body<IN_CH, HID, false>(blockIdx.x, A, Wh, Wl, dinv, h_out, M);
}

// gemm2: A (out1) is bf16 — no A split, 2 MFMAs per fragment
__launch_bounds__(512, 4)
__global__ void k_gemm2(const u16* __restrict__ A,
                        const u16* __restrict__ Wh, const u16* __restrict__ Wl,
                        const float* __restrict__ dinv, u16* __restrict__ h_out, int M) {
    gemm_body<HID, LAT, true>(blockIdx.x, A, Wh, Wl, dinv, h_out, M);
}

// ---------------- aggregates (node-major bf16 h, 16 B/lane gathers, 8-deep MLP) ----------------

__device__ inline void acc8(float* a, uint4 v) {
    a[0] += __uint_as_float(v.x << 16);
    a[1] += __uint_as_float(v.x & 0xFFFF0000u);
    a[2] += __uint_as_float(v.y << 16);
    a[3] += __uint_as_float(v.y & 0xFFFF0000u);
    a[4] += __uint_as_float(v.z << 16);
    a[5] += __uint_as_float(v.z & 0xFFFF0000u);
    a[6] += __uint_as_float(v.w << 16);
    a[7] += __uint_as_float(v.w & 0xFFFF0000u);
}

// OUT_BF16: store 8 bf16 (16 B) per thread (out feeds gemm2); else f32 pair of 16 B.
template<int C, bool RELU, bool OUT_BF16>
__global__ void k_aggregate(const int* __restrict__ row_ptr,
                            const int* __restrict__ row_end,
                            const int* __restrict__ csr,
                            const u16* __restrict__ h,
                            const float* __restrict__ dinv,
                            const float* __restrict__ bias,
                            void* __restrict__ out_v, int n) {
    constexpr int QSHIFT = (C == 128) ? 4 : 3;     // C/8 threads per node
    long long tid = (long long)blockIdx.x * blockDim.x + threadIdx.x;
    int node = (int)(tid >> QSHIFT);
    if (node >= n) return;
    int c = ((int)tid & ((1 << QSHIFT) - 1)) * 8;

    int k   = row_ptr[node];
    int end = row_end[node];

    float a[8] = {0.f, 0.f, 0.f, 0.f, 0.f, 0.f, 0.f, 0.f};
    acc8(a, *(const uint4*)&h[(size_t)node * C + c]);    // self-loop term

    for (; k + 8 <= end; k += 8) {                        // 8 gathers in flight
        int s0 = csr[k],     s1 = csr[k + 1], s2 = csr[k + 2], s3 = csr[k + 3];
        int s4 = csr[k + 4], s5 = csr[k + 5], s6 = csr[k + 6], s7 = csr[k + 7];
        uint4 v0 = *(const uint4*)&h[(size_t)s0 * C + c];
        uint4 v1 = *(const uint4*)&h[(size_t)s1 * C + c];
        uint4 v2 = *(const uint4*)&h[(size_t)s2 * C + c];
        uint4 v3 = *(const uint4*)&h[(size_t)s3 * C + c];
        uint4 v4 = *(const uint4*)&h[(size_t)s4 * C + c];
        uint4 v5 = *(const uint4*)&h[(size_t)s5 * C + c];
        uint4 v6 = *(const uint4*)&h[(size_t)s6 * C + c];
        uint4 v7 = *(const uint4*)&h[(size_t)s7 * C + c];
        acc8(a, v0); acc8(a, v1); acc8(a, v2); acc8(a, v3);
        acc8(a, v4); acc8(a, v5); acc8(a, v6); acc8(a, v7);
    }
    if (k + 4 <= end) {
        int s0 = csr[k], s1 = csr[k + 1], s2 = csr[k + 2], s3 = csr[k + 3];
        uint4 v0 = *(const uint4*)&h[(size_t)s0 * C + c];
        uint4 v1 = *(const uint4*)&h[(size_t)s1 * C + c];
        uint4 v2 = *(const uint4*)&h[(size_t)s2 * C + c];
        uint4 v3 = *(const uint4*)&h[(size_t)s3 * C + c];
        acc8(a, v0); acc8(a, v1); acc8(a, v2); acc8(a, v3);
        k += 4;
    }
    for (; k < end; ++k) {
        int s0 = csr[k];
        acc8(a, *(const uint4*)&h[(size_t)s0 * C + c]);
    }

    float dvn = dinv[node];
    float4 b0 = *(const float4*)&bias[c];
    float4 b1 = *(const float4*)&bias[c + 4];
    float o[8];
    o[0] = fmaf(a[0], dvn, b0.x);
    o[1] = fmaf(a[1], dvn, b0.y);
    o[2] = fmaf(a[2], dvn, b0.z);
    o[3] = fmaf(a[3], dvn, b0.w);
    o[4] = fmaf(a[4], dvn, b1.x);
    o[5] = fmaf(a[5], dvn, b1.y);
    o[6] = fmaf(a[6], dvn, b1.z);
    o[7] = fmaf(a[7], dvn, b1.w);
    if (RELU) {
#pragma unroll
        for (int j = 0; j < 8; ++j) o[j] = fmaxf(o[j], 0.f);
    }
    if (OUT_BF16) {
        u16 r[8];
#pragma unroll
        for (int j = 0; j < 8; ++j) r[j] = f2bf(o[j]);
        *(uint4*)&((u16*)out_v)[(size_t)node * C + c] = *(const uint4*)r;
    } else {
        float* out = (float*)out_v;
        *(f32x4*)&out[(size_t)node * C + c]     = *(const f32x4*)&o[0];
        *(f32x4*)&out[(size_t)node * C + c + 4] = *(const f32x4*)&o[4];
    }
}

// ---------------- launch ----------------

extern "C" void kernel_launch(void* const* d_in, const int* in_sizes, int n_in,
                              void* d_out, int out_size, void* d_ws, size_t ws_size,
                              hipStream_t stream) {
    const float* x   = (const float*)d_in[0];
    const int*   ei  = (const int*)d_in[1];     // harness delivers integers as int32
    const float* W1  = (const float*)d_in[2];
    const float* b1  = (const float*)d_in[3];
    const float* W2  = (const float*)d_in[4];
    const float* b2  = (const float*)d_in[5];
    float*       out = (float*)d_out;

    const int N = in_sizes[0] / IN_CH;
    const int E = in_sizes[1] / 2;
    const int* esrc = ei;
    const int* edst = ei + E;

    const int NSB = (N + SBN - 1) / SBN;   // super-buckets (98)
    const int NBB = (E + EPB - 1) / EPB;   // bin blocks (196)
    const int GB  = (N + 63) / 64;         // gemm blocks

    char* ws = (char*)d_ws;
    int*   sb_fill = (int*)ws;    ws += (size_t)((NSB + 31) & ~31) * 4;
    u32*   sbe     = (u32*)ws;    ws += (size_t)NSB * SB_CAP * 4;   // SB-grouped edges
    int*   csr     = (int*)ws;    ws += (size_t)NSB * SB_CAP * 4;   // slotted CSR
    int*   row_ptr = (int*)ws;    ws += (size_t)N * 4;
    int*   row_end = (int*)ws;    ws += (size_t)N * 4;
    float* dinv    = (float*)ws;  ws += (size_t)N * 4;
    u16*   W1h     = (u16*)ws;    ws += (size_t)HID * IN_CH * 2;
    u16*   W1l     = (u16*)ws;    ws += (size_t)HID * IN_CH * 2;
    u16*   W2h     = (u16*)ws;    ws += (size_t)LAT * HID * 2;
    u16*   W2l     = (u16*)ws;    ws += (size_t)LAT * HID * 2;
    u16*   h1      = (u16*)ws;    ws += (size_t)N * HID * 2;   // bf16, dinv folded
    u16*   h2      = (u16*)ws;    ws += (size_t)N * LAT * 2;   // bf16, dinv folded
    u16*   out1    = (u16*)ws;    ws += (size_t)N * HID * 2;   // agg1 out (bf16, GEMM2's A)

    dim3 blk(256);

    // ---- prep ----
    k_zero   <<<1, 128, 0, stream>>>(sb_fill, NSB);
    k_split_w<<<(HID * IN_CH + 255) / 256, blk, 0, stream>>>(W1, W1h, W1l, HID * IN_CH);
    k_split_w<<<(LAT * HID + 255) / 256, blk, 0, stream>>>(W2, W2h, W2l, LAT * HID);

    // ---- coalesced-write CSR build ----
    k_bin_sb<<<NBB, dim3(512), 0, stream>>>(esrc, edst, sb_fill, sbe, E, NSB);
    k_sbsort<<<NSB * 2, dim3(512), 0, stream>>>(sb_fill, sbe, csr, row_ptr, row_end, dinv, N);

    // ---- layer 1: 256 -> 128, relu ----
    k_gemm1<<<GB, dim3(512), 0, stream>>>(x, W1h, W1l, dinv, h1, N);
    {
        long long tot = (long long)N * 16;
        k_aggregate<HID, true, true><<<(unsigned)((tot + 255) / 256), blk, 0, stream>>>(
            row_ptr, row_end, csr, h1, dinv, b1, out1, N);
    }

    // ---- layer 2: 128 -> 64 ----
    k_gemm2<<<GB, dim3(512), 0, stream>>>(out1, W2h, W2l, dinv, h2, N);
    {
        long long tot = (long long)N * 8;
        k_aggregate<LAT, false, false><<<(unsigned)((tot + 255) / 256), blk, 0, stream>>>(
            row_ptr, row_end, csr, h2, dinv, b2, out, N);
    }
}